// Round 5
// baseline (155.962 us; speedup 1.0000x reference)
//
#include <hip/hip_runtime.h>
#include <hip/hip_bf16.h>

// N=50000 nodes, F=64, H=2, E=800000.
// qk = x @ W_qk + b -> [N,H,2,F]; s[e,h] = <q[row],k[col]>; sparse softmax per row; mean heads.
// Softmax WITHOUT max subtraction (shift-invariant; |s| <~ 15, safe in fp32).
// Kernels: [gemm(+W-transpose+den-zero)] -> 4x [scores+exp+segsum quarter] -> [normalize].
// R7 lesson: NO grid.sync on MI355X (cg barrier cost ~190us/sync at 1024 blocks).
// R1: K2 atomics -> __hip_atomic_fetch_add (agent scope, relaxed); gathers batched.
// R2: K1 transposed-MFMA epilogue (ushort4 stores), 782 blocks.
// R3 lesson: K2 counters: FETCH 173MB @ ~3.0TB/s beyond-L2, VALU 27%, occ 68%.
// R4 lesson: 2x MLP/thread (VGPR 52, occ 36%) -> identical 3.0TB/s. K2 is pinned at a
//     per-CU miss-queue/fabric cap for random line gathers; source-level MLP irrelevant.
//     fp8 (accuracy) and edge-sort (~40us pre-pass vs ~25us saved) both rejected.
// R5: DIAGNOSTIC round. K2 reverted to R3 4-edge form, split into 4 equal-range
//     dispatches (~15us each) so any hidden dispatch >15us (K1? K3? harness memset?)
//     surfaces in the top-5 window. Work byte-identical.
// MFMA 16x16x32 bf16 layouts (HW-verified): A[m=l&15][k=quad*8+j], B[k=quad*8+j][n=l&15],
// D col=l&15 row=quad*4+reg.

#define NFEAT 64
#define NCOL  256   // 2*H*F
#define WT_STRIDE 72  // shorts; 144B row stride: 16B-aligned, bank-shift 4 (2-way reads)

typedef __attribute__((ext_vector_type(8))) short bf16x8;
typedef __attribute__((ext_vector_type(4))) float f32x4;
typedef __attribute__((ext_vector_type(4))) unsigned int u32x4;
typedef __attribute__((ext_vector_type(4))) unsigned short u16x4;

__device__ __forceinline__ unsigned short f2bf(float f) {
    union { __hip_bfloat16 h; unsigned short u; } cv;
    cv.h = __float2bfloat16(f);
    return cv.u;
}

__device__ __forceinline__ float dot_bf16x2(unsigned a, unsigned b) {
    float alo = __uint_as_float(a << 16), ahi = __uint_as_float(a & 0xFFFF0000u);
    float blo = __uint_as_float(b << 16), bhi = __uint_as_float(b & 0xFFFF0000u);
    return alo * blo + ahi * bhi;
}

// ---------------- Kernel 1: qk projection via MFMA, transposed orientation ----------------
__global__ __launch_bounds__(256) void gemm_qk_mfma(
    const float* __restrict__ x, const float* __restrict__ W,
    const float* __restrict__ b,
    unsigned short* __restrict__ qo, unsigned short* __restrict__ ko,
    float* __restrict__ den, int N)
{
    __shared__ unsigned short WtL[NCOL * WT_STRIDE];  // 36.9 KB
    __shared__ float bL[NCOL];                        // 1 KB
    const int tid = threadIdx.x;

    // stage + transpose: W[k][c] (coalesced read) -> WtL[c*72 + k]
    for (int i = tid; i < NFEAT * NCOL; i += 256) {
        const int kk = i >> 8, c = i & 255;
        WtL[c * WT_STRIDE + kk] = f2bf(W[i]);
    }
    bL[tid] = b[tid];

    // zero denom: 782 blocks * 256 = 200192 >= 2N
    const int t = blockIdx.x * 256 + tid;
    if (t < 2 * N) den[t] = 0.f;

    const int lane = tid & 63;
    const int wv   = tid >> 6;
    const int l15  = lane & 15;
    const int quad = lane >> 4;
    const int base = blockIdx.x * 64 + wv * 16;
    __syncthreads();

    if (base >= N) return;

    // B-frag (x): lane supplies B[k=quad*8+j][n=l15] = x[base+l15][k]; two K-halves.
    int m = base + l15;
    if (m >= N) m = N - 1;                           // clamp (stores guarded)
    const float* xp = x + (size_t)m * NFEAT + quad * 8;
    bf16x8 xf[2];
#pragma unroll
    for (int ks = 0; ks < 2; ++ks) {
        float4 a0 = *(const float4*)(xp + ks * 32);
        float4 a1 = *(const float4*)(xp + ks * 32 + 4);
        bf16x8 f;
        f[0] = f2bf(a0.x); f[1] = f2bf(a0.y); f[2] = f2bf(a0.z); f[3] = f2bf(a0.w);
        f[4] = f2bf(a1.x); f[5] = f2bf(a1.y); f[6] = f2bf(a1.z); f[7] = f2bf(a1.w);
        xf[ks] = f;
    }

    const int mst = base + l15;                      // store row (unclamped)
    const bool mok = (mst < N);

#pragma unroll 4
    for (int ct = 0; ct < 16; ++ct) {
        // A-frag (Wt): A[row=c=ct*16+l15][k=quad*8+j]
        const int c = ct * 16 + l15;
        bf16x8 wt0 = *(const bf16x8*)(WtL + (size_t)c * WT_STRIDE + quad * 8);
        bf16x8 wt1 = *(const bf16x8*)(WtL + (size_t)c * WT_STRIDE + 32 + quad * 8);

        f32x4 acc = {0.f, 0.f, 0.f, 0.f};
        acc = __builtin_amdgcn_mfma_f32_16x16x32_bf16(wt0, xf[0], acc, 0, 0, 0);
        acc = __builtin_amdgcn_mfma_f32_16x16x32_bf16(wt1, xf[1], acc, 0, 0, 0);

        // lane holds out[mst][c0..c0+3], c0 = ct*16 + quad*4
        const int c0 = ct * 16 + quad * 4;
        const float4 b4 = *(const float4*)&bL[c0];
        u16x4 pk;
        pk[0] = f2bf(acc[0] + b4.x);
        pk[1] = f2bf(acc[1] + b4.y);
        pk[2] = f2bf(acc[2] + b4.z);
        pk[3] = f2bf(acc[3] + b4.w);
        const int h  = c0 >> 7;
        const int f0 = c0 & 63;
        unsigned short* dst = ((c0 >> 6) & 1) ? ko : qo;
        if (mok)
            *(u16x4*)(dst + (size_t)mst * 128 + h * 64 + f0) = pk;
    }
}

// ---------------- Kernel 2: scores -> exp -> segment-sum, 4 edges per 16-lane group ----------------
// Processes edge range [e0, e1). E is the row/col array stride.
__global__ __launch_bounds__(256) void edge_scores_exp(
    const unsigned short* __restrict__ q, const unsigned short* __restrict__ k,
    const int* __restrict__ ei, float* __restrict__ ex_out,
    float* __restrict__ denom, int E, int e0, int e1)
{
    const int grp  = (int)((blockIdx.x * 256 + threadIdx.x) >> 4);
    const int lane = threadIdx.x & 15;
    const int g0   = e0 + grp * 4;
    if (g0 >= e1) return;

    int v = 0;
    if (lane < 4)      v = ei[g0 + lane];
    else if (lane < 8) v = ei[E + g0 + (lane - 4)];
    int rows[4], cols[4];
#pragma unroll
    for (int i = 0; i < 4; ++i) {
        rows[i] = __shfl(v, i, 16);
        cols[i] = __shfl(v, 4 + i, 16);
    }

    u32x4 qa[4], ka[4];
#pragma unroll
    for (int i = 0; i < 4; ++i) {
        qa[i] = ((const u32x4*)(q + (size_t)rows[i] * 128))[lane];
        ka[i] = ((const u32x4*)(k + (size_t)cols[i] * 128))[lane];
    }
    asm volatile("" :: "v"(qa[0]), "v"(qa[1]), "v"(qa[2]), "v"(qa[3]),
                       "v"(ka[0]), "v"(ka[1]), "v"(ka[2]), "v"(ka[3]));

#pragma unroll
    for (int i = 0; i < 4; ++i) {
        float p = dot_bf16x2(qa[i][0], ka[i][0]) + dot_bf16x2(qa[i][1], ka[i][1])
                + dot_bf16x2(qa[i][2], ka[i][2]) + dot_bf16x2(qa[i][3], ka[i][3]);
        p += __shfl_xor(p, 1);
        p += __shfl_xor(p, 2);
        p += __shfl_xor(p, 4);
        if ((lane & 7) == 0 && g0 + i < e1) {
            const int h  = lane >> 3;
            const float e = __expf(p);
            ex_out[(size_t)(g0 + i) * 2 + h] = e;
            // Native fire-and-forget f32 atomic, agent scope (cross-XCD correct).
            __hip_atomic_fetch_add(&denom[(size_t)rows[i] * 2 + h], e,
                                   __ATOMIC_RELAXED, __HIP_MEMORY_SCOPE_AGENT);
        }
    }
}

// ---------------- Kernel 3: normalize + mean over heads ----------------
__global__ __launch_bounds__(256) void edge_out_k(
    const int* __restrict__ ei, const float* __restrict__ ex,
    const float* __restrict__ denom, float* __restrict__ out, int E)
{
    const int e = blockIdx.x * 256 + threadIdx.x;
    if (e >= E) return;
    const int row = ei[e];
    const float2 exv = *(const float2*)&ex[(size_t)e * 2];
    const float2 dv  = *(const float2*)&denom[(size_t)row * 2];
    out[e] = 0.5f * (exv.x / dv.x + exv.y / dv.y);
}

extern "C" void kernel_launch(void* const* d_in, const int* in_sizes, int n_in,
                              void* d_out, int out_size, void* d_ws, size_t ws_size,
                              hipStream_t stream)
{
    const float* x   = (const float*)d_in[0];
    const float* W   = (const float*)d_in[1];
    const float* b   = (const float*)d_in[2];
    const int*   ei  = (const int*)d_in[3];
    float*       out = (float*)d_out;

    const int N = in_sizes[0] / NFEAT;     // 50000
    const int E = in_sizes[3] / 2;         // 800000

    char* ws = (char*)d_ws;
    size_t off = 0;
    auto alloc = [&](size_t bytes) { void* p = ws + off; off += (bytes + 255) & ~(size_t)255; return p; };
    unsigned short* q_ws  = (unsigned short*)alloc((size_t)N * 128 * 2);        // 12.8 MB
    unsigned short* k_ws  = (unsigned short*)alloc((size_t)N * 128 * 2);        // 12.8 MB
    float*          ex_ws = (float*)alloc((size_t)E * 2 * sizeof(float));       // 6.4 MB
    float*          den_ws= (float*)alloc((size_t)N * 2 * sizeof(float));       // 0.4 MB
    (void)ws_size;

    gemm_qk_mfma<<<(N + 63) / 64, 256, 0, stream>>>(x, W, b, q_ws, k_ws, den_ws, N);

    // K2 split into 4 equal edge ranges (diagnostic: top-5 resolution ~15us).
    const int EQ = (E + 3) / 4;
    for (int part = 0; part < 4; ++part) {
        const int e0 = part * EQ;
        const int e1 = (part == 3) ? E : (e0 + EQ);
        const int ngrp = (e1 - e0 + 3) / 4;
        const int nblk = ((size_t)ngrp * 16 + 255) / 256;
        edge_scores_exp<<<nblk, 256, 0, stream>>>(q_ws, k_ws, ei, ex_ws, den_ws, E, e0, e1);
    }

    edge_out_k<<<(E + 255) / 256, 256, 0, stream>>>(ei, ex_ws, den_ws, out, E);
}

// Round 6
// 141.706 us; speedup vs baseline: 1.1006x; 1.1006x over previous
//
#include <hip/hip_runtime.h>
#include <hip/hip_bf16.h>

// N=50000 nodes, F=64, H=2, E=800000.
// qk = x @ W_qk + b -> [N,H,2,F]; s[e,h] = <q[row],k[col]>; sparse softmax per row; mean heads.
// Softmax WITHOUT max subtraction (shift-invariant; |s| <~ 15, safe in fp32).
// 3 kernels: [gemm(+W-transpose+den-zero)] -> [scores+exp+segsum] -> [normalize].
// TIME BUDGET (closed in R5): harness ws-poison fill 44us (256MiB @ 6.1TB/s, fixed) +
//   K2 58us (random-gather cap: 3.0TB/s beyond-L2, invariant to MLP/occupancy (R4)) +
//   K1 ~10us + K3 ~5us + ~4.7us/dispatch graph gaps. Floor ~137us, best measured 141.2.
// R7 lesson: NO grid.sync on MI355X (cg barrier ~190us/sync). fp8 rejected (error analysis:
//   score err ~0.2-0.5 abs -> exp err 20-50%, absmax already 0.0117). Edge-sort rejected
//   (~40us pre-pass vs ~25us saved). K2 split rejected (R5: +4.7us per extra dispatch).
// R1: K2 atomics -> __hip_atomic_fetch_add (agent scope, relaxed); gathers batched.
// R2: K1 transposed-MFMA epilogue (ushort4 stores), 782 blocks.
// MFMA 16x16x32 bf16 layouts (HW-verified): A[m=l&15][k=quad*8+j], B[k=quad*8+j][n=l&15],
// D col=l&15 row=quad*4+reg.

#define NFEAT 64
#define NCOL  256   // 2*H*F
#define WT_STRIDE 72  // shorts; 144B row stride: 16B-aligned, bank-shift 4 (2-way reads)

typedef __attribute__((ext_vector_type(8))) short bf16x8;
typedef __attribute__((ext_vector_type(4))) float f32x4;
typedef __attribute__((ext_vector_type(4))) unsigned int u32x4;
typedef __attribute__((ext_vector_type(4))) unsigned short u16x4;

__device__ __forceinline__ unsigned short f2bf(float f) {
    union { __hip_bfloat16 h; unsigned short u; } cv;
    cv.h = __float2bfloat16(f);
    return cv.u;
}

__device__ __forceinline__ float dot_bf16x2(unsigned a, unsigned b) {
    float alo = __uint_as_float(a << 16), ahi = __uint_as_float(a & 0xFFFF0000u);
    float blo = __uint_as_float(b << 16), bhi = __uint_as_float(b & 0xFFFF0000u);
    return alo * blo + ahi * bhi;
}

// ---------------- Kernel 1: qk projection via MFMA, transposed orientation ----------------
// Block: 256 thr = 4 waves; each wave 16 rows (m = base + wv*16 + l15) x 256 cols.
// D = Wt_tile (A, rows=c) x X^T_tile (B, cols=m): lane (quad,l15) holds
// out[m = base+wv*16+l15][c = ct*16 + quad*4 + r], r=0..3 -> one 8B ushort4 store per ct.
__global__ __launch_bounds__(256) void gemm_qk_mfma(
    const float* __restrict__ x, const float* __restrict__ W,
    const float* __restrict__ b,
    unsigned short* __restrict__ qo, unsigned short* __restrict__ ko,
    float* __restrict__ den, int N)
{
    __shared__ unsigned short WtL[NCOL * WT_STRIDE];  // 36.9 KB
    __shared__ float bL[NCOL];                        // 1 KB
    const int tid = threadIdx.x;

    // stage + transpose: W[k][c] (coalesced read) -> WtL[c*72 + k]
    for (int i = tid; i < NFEAT * NCOL; i += 256) {
        const int kk = i >> 8, c = i & 255;
        WtL[c * WT_STRIDE + kk] = f2bf(W[i]);
    }
    bL[tid] = b[tid];

    // zero denom: 782 blocks * 256 = 200192 >= 2N
    const int t = blockIdx.x * 256 + tid;
    if (t < 2 * N) den[t] = 0.f;

    const int lane = tid & 63;
    const int wv   = tid >> 6;
    const int l15  = lane & 15;
    const int quad = lane >> 4;
    const int base = blockIdx.x * 64 + wv * 16;
    __syncthreads();

    if (base >= N) return;

    // B-frag (x): lane supplies B[k=quad*8+j][n=l15] = x[base+l15][k]; two K-halves.
    int m = base + l15;
    if (m >= N) m = N - 1;                           // clamp (stores guarded)
    const float* xp = x + (size_t)m * NFEAT + quad * 8;
    bf16x8 xf[2];
#pragma unroll
    for (int ks = 0; ks < 2; ++ks) {
        float4 a0 = *(const float4*)(xp + ks * 32);
        float4 a1 = *(const float4*)(xp + ks * 32 + 4);
        bf16x8 f;
        f[0] = f2bf(a0.x); f[1] = f2bf(a0.y); f[2] = f2bf(a0.z); f[3] = f2bf(a0.w);
        f[4] = f2bf(a1.x); f[5] = f2bf(a1.y); f[6] = f2bf(a1.z); f[7] = f2bf(a1.w);
        xf[ks] = f;
    }

    const int mst = base + l15;                      // store row (unclamped)
    const bool mok = (mst < N);

#pragma unroll 4
    for (int ct = 0; ct < 16; ++ct) {
        // A-frag (Wt): A[row=c=ct*16+l15][k=quad*8+j]
        const int c = ct * 16 + l15;
        bf16x8 wt0 = *(const bf16x8*)(WtL + (size_t)c * WT_STRIDE + quad * 8);
        bf16x8 wt1 = *(const bf16x8*)(WtL + (size_t)c * WT_STRIDE + 32 + quad * 8);

        f32x4 acc = {0.f, 0.f, 0.f, 0.f};
        acc = __builtin_amdgcn_mfma_f32_16x16x32_bf16(wt0, xf[0], acc, 0, 0, 0);
        acc = __builtin_amdgcn_mfma_f32_16x16x32_bf16(wt1, xf[1], acc, 0, 0, 0);

        // lane holds out[mst][c0..c0+3], c0 = ct*16 + quad*4
        const int c0 = ct * 16 + quad * 4;
        const float4 b4 = *(const float4*)&bL[c0];
        u16x4 pk;
        pk[0] = f2bf(acc[0] + b4.x);
        pk[1] = f2bf(acc[1] + b4.y);
        pk[2] = f2bf(acc[2] + b4.z);
        pk[3] = f2bf(acc[3] + b4.w);
        const int h  = c0 >> 7;
        const int f0 = c0 & 63;
        unsigned short* dst = ((c0 >> 6) & 1) ? ko : qo;
        if (mok)
            *(u16x4*)(dst + (size_t)mst * 128 + h * 64 + f0) = pk;
    }
}

// ---------------- Kernel 2: scores -> exp -> segment-sum, 4 edges per 16-lane group ----------------
__global__ __launch_bounds__(256) void edge_scores_exp(
    const unsigned short* __restrict__ q, const unsigned short* __restrict__ k,
    const int* __restrict__ ei, float* __restrict__ ex_out,
    float* __restrict__ denom, int E)
{
    const int grp  = (int)((blockIdx.x * 256 + threadIdx.x) >> 4);
    const int lane = threadIdx.x & 15;
    const int g0   = grp * 4;
    if (g0 >= E) return;

    int v = 0;
    if (lane < 4)      v = ei[g0 + lane];
    else if (lane < 8) v = ei[E + g0 + (lane - 4)];
    int rows[4], cols[4];
#pragma unroll
    for (int i = 0; i < 4; ++i) {
        rows[i] = __shfl(v, i, 16);
        cols[i] = __shfl(v, 4 + i, 16);
    }

    // All 8 row-gathers issued before any consumption.
    u32x4 qa[4], ka[4];
#pragma unroll
    for (int i = 0; i < 4; ++i) {
        qa[i] = ((const u32x4*)(q + (size_t)rows[i] * 128))[lane];
        ka[i] = ((const u32x4*)(k + (size_t)cols[i] * 128))[lane];
    }
    asm volatile("" :: "v"(qa[0]), "v"(qa[1]), "v"(qa[2]), "v"(qa[3]),
                       "v"(ka[0]), "v"(ka[1]), "v"(ka[2]), "v"(ka[3]));

#pragma unroll
    for (int i = 0; i < 4; ++i) {
        float p = dot_bf16x2(qa[i][0], ka[i][0]) + dot_bf16x2(qa[i][1], ka[i][1])
                + dot_bf16x2(qa[i][2], ka[i][2]) + dot_bf16x2(qa[i][3], ka[i][3]);
        p += __shfl_xor(p, 1);
        p += __shfl_xor(p, 2);
        p += __shfl_xor(p, 4);
        if ((lane & 7) == 0 && g0 + i < E) {
            const int h  = lane >> 3;
            const float e = __expf(p);
            ex_out[(size_t)(g0 + i) * 2 + h] = e;
            // Native fire-and-forget f32 atomic, agent scope (cross-XCD correct).
            __hip_atomic_fetch_add(&denom[(size_t)rows[i] * 2 + h], e,
                                   __ATOMIC_RELAXED, __HIP_MEMORY_SCOPE_AGENT);
        }
    }
}

// ---------------- Kernel 3: normalize + mean over heads ----------------
__global__ __launch_bounds__(256) void edge_out_k(
    const int* __restrict__ ei, const float* __restrict__ ex,
    const float* __restrict__ denom, float* __restrict__ out, int E)
{
    const int e = blockIdx.x * 256 + threadIdx.x;
    if (e >= E) return;
    const int row = ei[e];
    const float2 exv = *(const float2*)&ex[(size_t)e * 2];
    const float2 dv  = *(const float2*)&denom[(size_t)row * 2];
    out[e] = 0.5f * (exv.x / dv.x + exv.y / dv.y);
}

extern "C" void kernel_launch(void* const* d_in, const int* in_sizes, int n_in,
                              void* d_out, int out_size, void* d_ws, size_t ws_size,
                              hipStream_t stream)
{
    const float* x   = (const float*)d_in[0];
    const float* W   = (const float*)d_in[1];
    const float* b   = (const float*)d_in[2];
    const int*   ei  = (const int*)d_in[3];
    float*       out = (float*)d_out;

    const int N = in_sizes[0] / NFEAT;     // 50000
    const int E = in_sizes[3] / 2;         // 800000

    char* ws = (char*)d_ws;
    size_t off = 0;
    auto alloc = [&](size_t bytes) { void* p = ws + off; off += (bytes + 255) & ~(size_t)255; return p; };
    unsigned short* q_ws  = (unsigned short*)alloc((size_t)N * 128 * 2);        // 12.8 MB
    unsigned short* k_ws  = (unsigned short*)alloc((size_t)N * 128 * 2);        // 12.8 MB
    float*          ex_ws = (float*)alloc((size_t)E * 2 * sizeof(float));       // 6.4 MB
    float*          den_ws= (float*)alloc((size_t)N * 2 * sizeof(float));       // 0.4 MB
    (void)ws_size;

    gemm_qk_mfma<<<(N + 63) / 64, 256, 0, stream>>>(x, W, b, q_ws, k_ws, den_ws, N);
    edge_scores_exp<<<((size_t)(E + 3) / 4 * 16 + 255) / 256, 256, 0, stream>>>(q_ws, k_ws, ei, ex_ws, den_ws, E);
    edge_out_k<<<(E + 255) / 256, 256, 0, stream>>>(ei, ex_ws, den_ws, out, E);
}